// Round 5
// baseline (2573.507 us; speedup 1.0000x reference)
//
#include <hip/hip_runtime.h>

// EGKN: E(n) graph kernel network.
#define NN 10000      // nodes
#define NE 300000     // edges
#define DEPTH 4

typedef unsigned int   u32;
typedef unsigned short u16;
typedef unsigned char  u8;

// fp16 encode/decode via hardware v_cvt (with saturation on encode)
__device__ __forceinline__ u32 f2h(float f) {
    f = fminf(fmaxf(f, -60000.f), 60000.f);
    _Float16 h = (_Float16)f;
    return (u32)__builtin_bit_cast(u16, h);
}
__device__ __forceinline__ float h2f(u16 b) {
    return (float)__builtin_bit_cast(_Float16, b);
}
__device__ __forceinline__ float hlo(u32 w) { return h2f((u16)(w & 0xffffu)); }
__device__ __forceinline__ float hhi(u32 w) { return h2f((u16)(w >> 16)); }
// signed-int8 decode from a byte
__device__ __forceinline__ float sx8(u32 b) { return (float)(((int)(b & 0xffu) ^ 0x80) - 128); }

// ---------------------------------------------------------------------------
__global__ void sentinel_kernel(float* out, int n, float val) {
    int i = blockIdx.x * 256 + threadIdx.x;
    if (i < n) out[i] = val;
}

// ---------------------------------------------------------------------------
// edge_index dtype normalization (int64 vs int32)
// ---------------------------------------------------------------------------
__global__ void detect_idx_kernel(const int* __restrict__ ei, int* __restrict__ flag) {
    __shared__ int nz;
    if (threadIdx.x == 0) nz = 0;
    __syncthreads();
    if (ei[threadIdx.x * 2 + 1] != 0) atomicAdd(&nz, 1);
    __syncthreads();
    if (threadIdx.x == 0) *flag = (nz == 0) ? 1 : 0;   // 1 => int64
}

__global__ __launch_bounds__(256) void convert_idx_kernel(
    const int* __restrict__ ei, const int* __restrict__ flag,
    int* __restrict__ ridx, int* __restrict__ cidx)
{
    int e = blockIdx.x * 256 + threadIdx.x;
    if (e >= 2 * NE) return;
    const int is64 = *flag;
    int v = is64 ? ei[2 * e] : ei[e];
    if (e < NE) ridx[e] = v; else cidx[e - NE] = v;
}

// ---------------------------------------------------------------------------
// init: h = x @ fc1_w + fc1_b   [NN,32];  coord = coords_init copy
// ---------------------------------------------------------------------------
__global__ __launch_bounds__(256) void init_nodes_kernel(
    const float* __restrict__ x, const float* __restrict__ fc1w,
    const float* __restrict__ fc1b, const float* __restrict__ ci,
    float* __restrict__ h, float* __restrict__ coord)
{
    int idx = blockIdx.x * 256 + threadIdx.x;
    if (idx < NN * 32) {
        int v = idx >> 5, f = idx & 31;
        float acc = fc1b[f];
#pragma unroll
        for (int i = 0; i < 3; i++) acc += x[v * 3 + i] * fc1w[i * 32 + f];
        h[idx] = acc;
    }
    if (idx < NN * 3) coord[idx] = ci[idx];
}

// ---------------------------------------------------------------------------
// CSR-by-col build: counts, scan, scatter
// ---------------------------------------------------------------------------
__global__ __launch_bounds__(256) void count_kernel(
    const int* __restrict__ ridx, const int* __restrict__ cidx,
    int* __restrict__ rowcnt, int* __restrict__ colcnt)
{
    int e = blockIdx.x * 256 + threadIdx.x;
    if (e < NE) { atomicAdd(&rowcnt[ridx[e]], 1); atomicAdd(&colcnt[cidx[e]], 1); }
}

__global__ void scan_kernel(const int* __restrict__ colcnt, const int* __restrict__ rowcnt,
                            int* __restrict__ cstart, int* __restrict__ cnext,
                            float* __restrict__ invc)
{
    __shared__ int part[256];
    const int t = threadIdx.x;
    int sum = 0;
    for (int i = 0; i < 40; i++) { int v = t * 40 + i; if (v < NN) sum += colcnt[v]; }
    part[t] = sum;
    __syncthreads();
    if (t == 0) {
        int run = 0;
        for (int i = 0; i < 256; i++) { int tmp = part[i]; part[i] = run; run += tmp; }
    }
    __syncthreads();
    int run = part[t];
    for (int i = 0; i < 40; i++) {
        int v = t * 40 + i;
        if (v < NN) { cstart[v] = run; cnext[v] = run; run += colcnt[v]; }
    }
    if (t == 255) cstart[NN] = run;
    for (int v = t; v < NN; v += 256) invc[v] = 1.0f / fmaxf((float)rowcnt[v], 1.0f);
}

__global__ __launch_bounds__(256) void scatter_kernel(
    const int* __restrict__ cidx, int* __restrict__ cnext, int* __restrict__ elist)
{
    int e = blockIdx.x * 256 + threadIdx.x;
    if (e < NE) { int pos = atomicAdd(&cnext[cidx[e]], 1); elist[pos] = e; }
}

// ---------------------------------------------------------------------------
// k2 MLP: edge_attr[6] -> 128 -> 256 (relu both). 32 edges/block.
// fk2=0: fp16 [e][256].  fk2=1: uint8 [e][256] + per-edge scale k2s[e]
// (k2 >= 0 after relu, so unsigned with scale = rowmax/255).
// ---------------------------------------------------------------------------
__global__ __launch_bounds__(256) void mlp_k2_kernel(
    const float* __restrict__ ea,
    const float* __restrict__ w1, const float* __restrict__ b1,
    const float* __restrict__ w2, const float* __restrict__ b2,
    u8* __restrict__ k2base, float* __restrict__ k2s, int fk2)
{
    __shared__ __align__(16) float ea_s[32 * 6];
    __shared__ __align__(16) float k1_s[128 * 32];     // [kk][e]
    __shared__ __align__(16) float k2_s[32 * 260];     // [e][c], padded
    const int t  = threadIdx.x;
    const int e0 = blockIdx.x * 32;

    for (int idx = t; idx < 32 * 6; idx += 256)
        ea_s[idx] = ea[(size_t)e0 * 6 + idx];
    __syncthreads();

    // layer 1: [32,6] @ [6,128], relu
    for (int idx = t; idx < 128 * 32; idx += 256) {
        int kk = idx >> 5, e = idx & 31;
        float acc = b1[kk];
#pragma unroll
        for (int i = 0; i < 6; i++) acc += ea_s[e * 6 + i] * w1[i * 128 + kk];
        k1_s[kk * 32 + e] = fmaxf(acc, 0.f);
    }
    __syncthreads();

    // layer 2: [32,128] @ [128,256], relu. thread tile: 4 cols x 8 edges
    {
        const int c0 = (t & 63) * 4;
        const int eb = (t >> 6) * 8;
        float acc[4][8];
#pragma unroll
        for (int a = 0; a < 4; a++)
#pragma unroll
            for (int b = 0; b < 8; b++) acc[a][b] = 0.f;
        for (int kk = 0; kk < 128; kk++) {
            const float4 wv = *(const float4*)&w2[kk * 256 + c0];
            const float4 ka = *(const float4*)&k1_s[kk * 32 + eb];
            const float4 kb = *(const float4*)&k1_s[kk * 32 + eb + 4];
            const float ke[8] = {ka.x, ka.y, ka.z, ka.w, kb.x, kb.y, kb.z, kb.w};
            const float wc[4] = {wv.x, wv.y, wv.z, wv.w};
#pragma unroll
            for (int a = 0; a < 4; a++)
#pragma unroll
                for (int b = 0; b < 8; b++) acc[a][b] += wc[a] * ke[b];
        }
        const float bb0 = b2[c0], bb1 = b2[c0 + 1], bb2 = b2[c0 + 2], bb3 = b2[c0 + 3];
#pragma unroll
        for (int b = 0; b < 8; b++) {
            float4 v;
            v.x = fmaxf(acc[0][b] + bb0, 0.f);
            v.y = fmaxf(acc[1][b] + bb1, 0.f);
            v.z = fmaxf(acc[2][b] + bb2, 0.f);
            v.w = fmaxf(acc[3][b] + bb3, 0.f);
            *(float4*)&k2_s[(eb + b) * 260 + c0] = v;
        }
    }
    __syncthreads();

    // store k2: thread t -> edge el=t>>3, col-chunk q=t&7 (32 cols each)
    {
        const int el = t >> 3, q = t & 7;
        const size_t eglob = (size_t)e0 + el;
        if (fk2 == 0) {
            u16* outp = (u16*)k2base + eglob * 256 + q * 32;
#pragma unroll
            for (int u = 0; u < 8; u += 2) {
                float4 a = *(float4*)&k2_s[el * 260 + q * 32 + u * 4];
                float4 b = *(float4*)&k2_s[el * 260 + q * 32 + u * 4 + 4];
                uint4 o;
                o.x = f2h(a.x) | (f2h(a.y) << 16);
                o.y = f2h(a.z) | (f2h(a.w) << 16);
                o.z = f2h(b.x) | (f2h(b.y) << 16);
                o.w = f2h(b.z) | (f2h(b.w) << 16);
                *(uint4*)(outp + u * 4) = o;
            }
        } else {
            // per-edge max over the 8 lanes covering this edge (lanes el*8..el*8+7)
            float mx = 0.f;
#pragma unroll
            for (int u = 0; u < 32; u++) mx = fmaxf(mx, k2_s[el * 260 + q * 32 + u]);
            mx = fmaxf(mx, __shfl_xor(mx, 1, 8));
            mx = fmaxf(mx, __shfl_xor(mx, 2, 8));
            mx = fmaxf(mx, __shfl_xor(mx, 4, 8));
            const float sc  = mx / 255.f;
            const float inv = (mx > 0.f) ? 255.f / mx : 0.f;
            if (q == 0) k2s[eglob] = sc;
            u8* outp = k2base + eglob * 256 + q * 32;
            u32 w[8];
#pragma unroll
            for (int u = 0; u < 8; u++) {
                float4 a = *(float4*)&k2_s[el * 260 + q * 32 + u * 4];
                u32 q0 = (u32)fminf(rintf(a.x * inv), 255.f);
                u32 q1 = (u32)fminf(rintf(a.y * inv), 255.f);
                u32 q2 = (u32)fminf(rintf(a.z * inv), 255.f);
                u32 q3 = (u32)fminf(rintf(a.w * inv), 255.f);
                w[u] = q0 | (q1 << 8) | (q2 << 16) | (q3 << 24);
            }
            *(uint4*)outp        = make_uint4(w[0], w[1], w[2], w[3]);
            *(uint4*)(outp + 16) = make_uint4(w[4], w[5], w[6], w[7]);
        }
    }
}

// ---------------------------------------------------------------------------
// Bvec[v][i] = sum_j b3[i*32+j] * h[v][j]
// ---------------------------------------------------------------------------
__global__ __launch_bounds__(256) void bvec_kernel(
    const float* __restrict__ h, const float* __restrict__ b3, float* __restrict__ bvec)
{
    int idx = blockIdx.x * 256 + threadIdx.x;
    if (idx >= NN * 32) return;
    int v = idx >> 5, i = idx & 31;
    const float* hp = &h[(size_t)v * 32];
    const float* bp = &b3[i * 32];
    float acc = 0.f;
#pragma unroll
    for (int c = 0; c < 8; c++) {
        float4 hv = *(const float4*)&hp[c * 4];
        float4 bv = *(const float4*)&bp[c * 4];
        acc += hv.x * bv.x + hv.y * bv.y + hv.z * bv.z + hv.w * bv.w;
    }
    bvec[idx] = acc;
}

// ---------------------------------------------------------------------------
// w3 row-norm^2 max (for int8-G scale bound):  w3n = max_p ||w3_p||^2
// ---------------------------------------------------------------------------
__global__ __launch_bounds__(256) void w3norm_kernel(
    const float* __restrict__ w3, u32* __restrict__ w3n)
{
    const int p = blockIdx.x * 256 + threadIdx.x;   // 0..8191
    const float* wp = &w3[(size_t)(p >> 5) * 1024 + (size_t)(p & 31) * 32];
    float s2 = 0.f;
#pragma unroll
    for (int c = 0; c < 8; c++) {
        float4 a = *(const float4*)&wp[c * 4];
        s2 += a.x * a.x + a.y * a.y + a.z * a.z + a.w * a.w;
    }
#pragma unroll
    for (int off = 32; off >= 1; off >>= 1) s2 = fmaxf(s2, __shfl_xor(s2, off, 64));
    if ((threadIdx.x & 63) == 0) atomicMax(w3n, __float_as_uint(s2));
}

// gsc[v] = bound/127, ginv[v] = 127/bound; bound = ||h[v]|| * max_p ||w3_p||
__global__ __launch_bounds__(256) void gscale_kernel(
    const float* __restrict__ h, const u32* __restrict__ w3n,
    float* __restrict__ gsc, float* __restrict__ ginv)
{
    int v = blockIdx.x * 256 + threadIdx.x;
    if (v >= NN) return;
    const float* hp = &h[(size_t)v * 32];
    float s2 = 0.f;
#pragma unroll
    for (int c = 0; c < 8; c++) {
        float4 a = *(const float4*)&hp[c * 4];
        s2 += a.x * a.x + a.y * a.y + a.z * a.z + a.w * a.w;
    }
    float bound = sqrtf(s2) * sqrtf(__uint_as_float(*w3n));
    gsc[v]  = bound / 127.f;
    ginv[v] = (bound > 0.f) ? 127.f / bound : 0.f;
}

// ---------------------------------------------------------------------------
// G[v][kk*32+i] = sum_j w3[kk*1024 + i*32 + j] * h[v][j]
// fG=0: fp16. fG=1: int8 with per-node scale gsc[v].
// block: 128 nodes x 512 p-slice; thread: 2 consecutive p. Grid: (79, 16).
// ---------------------------------------------------------------------------
__global__ __launch_bounds__(256) void g_kernel(
    const float* __restrict__ h, const float* __restrict__ w3,
    u8* __restrict__ Gbase, const float* __restrict__ ginv, int fG)
{
    __shared__ __align__(16) float h_s[128 * 32];
    const int t  = threadIdx.x;
    const int v0 = blockIdx.x * 128;

    for (int i = t; i < 128 * 8; i += 256) {
        const int v = i >> 3, c = i & 7;
        float4 val = make_float4(0.f, 0.f, 0.f, 0.f);
        if (v0 + v < NN) val = *(const float4*)&h[(size_t)(v0 + v) * 32 + c * 4];
        *(float4*)&h_s[v * 32 + c * 4] = val;
    }
    __syncthreads();

    const int p0 = blockIdx.y * 512 + t * 2;
    float w0[32], w1[32];
    {
        const float* wp0 = &w3[(size_t)(p0 >> 5) * 1024 + (size_t)(p0 & 31) * 32];
        const float* wp1 = &w3[(size_t)((p0 + 1) >> 5) * 1024 + (size_t)((p0 + 1) & 31) * 32];
#pragma unroll
        for (int c = 0; c < 8; c++) {
            float4 a = *(const float4*)&wp0[c * 4];
            w0[c * 4] = a.x; w0[c * 4 + 1] = a.y; w0[c * 4 + 2] = a.z; w0[c * 4 + 3] = a.w;
            float4 b = *(const float4*)&wp1[c * 4];
            w1[c * 4] = b.x; w1[c * 4 + 1] = b.y; w1[c * 4 + 2] = b.z; w1[c * 4 + 3] = b.w;
        }
    }
    const int vmax = min(128, NN - v0);
    for (int v = 0; v < vmax; v++) {
        float a0 = 0.f, a1 = 0.f;
#pragma unroll
        for (int c = 0; c < 8; c++) {
            float4 hv = *(const float4*)&h_s[v * 32 + c * 4];
            a0 += hv.x * w0[c*4] + hv.y * w0[c*4+1] + hv.z * w0[c*4+2] + hv.w * w0[c*4+3];
            a1 += hv.x * w1[c*4] + hv.y * w1[c*4+1] + hv.z * w1[c*4+2] + hv.w * w1[c*4+3];
        }
        const size_t gi = (size_t)(v0 + v) * 8192 + p0;
        if (fG == 0) {
            *(u32*)((u16*)Gbase + gi) = f2h(a0) | (f2h(a1) << 16);
        } else {
            const float inv = ginv[v0 + v];
            int q0 = (int)fminf(fmaxf(rintf(a0 * inv), -127.f), 127.f);
            int q1 = (int)fminf(fmaxf(rintf(a1 * inv), -127.f), 127.f);
            *(u16*)(Gbase + gi) = (u16)((q0 & 0xff) | ((q1 & 0xff) << 8));
        }
    }
}

// ---------------------------------------------------------------------------
// Fused edge pass, one block per col-node n:
//   m[i] = Bvec[n][i] + sum_kk k2[e][kk]*G[n][kk*32+i]
//   agg[row] += m;  we = relu(m@cm1+b1)@cm2+b2;  dco[row] += (coord[row]-coord[n])*we
// LDS: G 16K (fp16 pairs) + k2 33.3K (fp32) + cm1 4K + eid 128B < 64K.
// ---------------------------------------------------------------------------
__global__ __launch_bounds__(256) void edge_kernel(
    const int* __restrict__ cstart, const int* __restrict__ elist,
    const int* __restrict__ ridx, const u8* __restrict__ k2base,
    const float* __restrict__ k2s, const u8* __restrict__ Gbase,
    const float* __restrict__ gsc, const float* __restrict__ coord,
    const float* __restrict__ cm1w, const float* __restrict__ cm1b,
    const float* __restrict__ cm2w, const float* __restrict__ cm2b,
    const float* __restrict__ bvec, float* __restrict__ agg,
    float* __restrict__ dco, int fk2, int fG)
{
    const int n   = blockIdx.x;
    const int s   = cstart[n];
    const int deg = cstart[n + 1] - s;
    if (deg == 0) return;
    const int t = threadIdx.x;

    __shared__ __align__(16) u32   G_su[4096];     // fp16 pairs
    __shared__ __align__(16) float k2_s[32 * 260];
    __shared__ float cm1_s[1024];
    __shared__ int   eid_s[32];

    if (fG == 0) {
        const uint4* gp = (const uint4*)Gbase + (size_t)n * 1024;
        for (int i = t; i < 1024; i += 256) *(uint4*)&G_su[i * 4] = gp[i];
    } else {
        const float sn = gsc[n];
        const u32* gp = (const u32*)(Gbase + (size_t)n * 8192);
        for (int i = t; i < 2048; i += 256) {
            u32 w = gp[i];
            float v0 = sx8(w) * sn, v1 = sx8(w >> 8) * sn;
            float v2 = sx8(w >> 16) * sn, v3 = sx8(w >> 24) * sn;
            G_su[2 * i]     = f2h(v0) | (f2h(v1) << 16);
            G_su[2 * i + 1] = f2h(v2) | (f2h(v3) << 16);
        }
    }
    for (int idx = t; idx < 1024; idx += 256) cm1_s[idx] = cm1w[idx];

    const int p    = t & 31;
    const int slot = t >> 5;
    const int phw  = p >> 1, psel = p & 1;
    const float bv    = bvec[n * 32 + p];
    const float cm1bp = cm1b[p];
    const float cm2p  = cm2w[p];
    const float cm2b0 = cm2b[0];
    const float cocol = (p < 3) ? coord[(size_t)n * 3 + p] : 0.f;

    const int rounds = (deg + 31) >> 5;
    for (int r = 0; r < rounds; r++) {
        __syncthreads();
        if (t < 32) eid_s[t] = (r * 32 + t < deg) ? elist[s + r * 32 + t] : -1;
        __syncthreads();
        // stage k2 rows for up to 32 edges (fp32 in LDS)
        {
            const int el = t >> 3, q = t & 7;
            const int eid = eid_s[el];
            float se = 0.f;
            if (eid >= 0 && fk2 == 1) se = k2s[eid];
#pragma unroll
            for (int j = 0; j < 8; j++) {
                const int cw = q + j * 8;
                float4 v = make_float4(0.f, 0.f, 0.f, 0.f);
                if (eid >= 0) {
                    if (fk2 == 0) {
                        uint2 w = ((const uint2*)k2base)[(size_t)eid * 64 + cw];
                        v.x = hlo(w.x); v.y = hhi(w.x); v.z = hlo(w.y); v.w = hhi(w.y);
                    } else {
                        u32 w = ((const u32*)k2base)[(size_t)eid * 64 + cw];
                        v.x = (float)(w & 255u) * se;
                        v.y = (float)((w >> 8) & 255u) * se;
                        v.z = (float)((w >> 16) & 255u) * se;
                        v.w = (float)(w >> 24) * se;
                    }
                }
                *(float4*)&k2_s[el * 260 + cw * 4] = v;
            }
        }
        __syncthreads();

        const int e0 = slot * 4;
        float m0 = bv, m1 = bv, m2 = bv, m3 = bv;
        for (int kk = 0; kk < 256; kk += 4) {
            u32 gw0 = G_su[(kk + 0) * 16 + phw];
            u32 gw1 = G_su[(kk + 1) * 16 + phw];
            u32 gw2 = G_su[(kk + 2) * 16 + phw];
            u32 gw3 = G_su[(kk + 3) * 16 + phw];
            const float g0 = psel ? hhi(gw0) : hlo(gw0);
            const float g1 = psel ? hhi(gw1) : hlo(gw1);
            const float g2 = psel ? hhi(gw2) : hlo(gw2);
            const float g3 = psel ? hhi(gw3) : hlo(gw3);
            float4 a = *(const float4*)&k2_s[(e0 + 0) * 260 + kk];
            m0 += a.x * g0 + a.y * g1 + a.z * g2 + a.w * g3;
            float4 b = *(const float4*)&k2_s[(e0 + 1) * 260 + kk];
            m1 += b.x * g0 + b.y * g1 + b.z * g2 + b.w * g3;
            float4 c = *(const float4*)&k2_s[(e0 + 2) * 260 + kk];
            m2 += c.x * g0 + c.y * g1 + c.z * g2 + c.w * g3;
            float4 d = *(const float4*)&k2_s[(e0 + 3) * 260 + kk];
            m3 += d.x * g0 + d.y * g1 + d.z * g2 + d.w * g3;
        }
        float mv[4] = {m0, m1, m2, m3};
#pragma unroll 1
        for (int e = 0; e < 4; e++) {
            const int eid = eid_s[e0 + e];
            if (eid < 0) continue;                  // uniform within the 32-lane slot
            const int row = ridx[eid];
            atomicAdd(&agg[(size_t)row * 32 + p], mv[e]);
            float tacc = cm1bp;
#pragma unroll
            for (int i = 0; i < 32; i++)
                tacc += __shfl(mv[e], i, 32) * cm1_s[i * 32 + p];
            float part = fmaxf(tacc, 0.f) * cm2p;
#pragma unroll
            for (int off = 16; off >= 1; off >>= 1) part += __shfl_xor(part, off, 32);
            const float we = part + cm2b0;
            if (p < 3) {
                const float d = coord[(size_t)row * 3 + p] - cocol;
                atomicAdd(&dco[(size_t)row * 3 + p], d * we);
            }
        }
    }
}

// ---------------------------------------------------------------------------
__global__ __launch_bounds__(256) void node_update_kernel(
    float* __restrict__ h, float* __restrict__ agg,
    float* __restrict__ coord, float* __restrict__ dco,
    const float* __restrict__ invc)
{
    int idx = blockIdx.x * 256 + threadIdx.x;
    if (idx < NN * 32) {
        int v = idx >> 5;
        h[idx] = fmaxf(h[idx] + agg[idx] * invc[v], 0.f);
        agg[idx] = 0.f;
    }
    if (idx < NN * 3) {
        coord[idx] += dco[idx] * invc[idx / 3];
        dco[idx] = 0.f;
    }
}

// ---------------------------------------------------------------------------
__global__ __launch_bounds__(256) void final_kernel(
    const float* __restrict__ h, const float* __restrict__ coord,
    const float* __restrict__ wa, const float* __restrict__ ba,
    const float* __restrict__ wb, const float* __restrict__ bb,
    float* __restrict__ out)
{
    const int lane = threadIdx.x & 63;
    const int v = blockIdx.x * 4 + (threadIdx.x >> 6);
    if (v >= NN) return;
    const float hreg = (lane < 32) ? h[(size_t)v * 32 + lane] : 0.f;
    float acc = ba[lane];
#pragma unroll
    for (int f = 0; f < 32; f++) acc += __shfl(hreg, f, 64) * wa[f * 64 + lane];
    float part = fmaxf(acc, 0.f) * wb[lane];
#pragma unroll
    for (int off = 32; off >= 1; off >>= 1) part += __shfl_xor(part, off, 64);
    if (lane == 0) out[v] = part + bb[0];
    if (lane < 3) out[NN + (size_t)v * 3 + lane] = coord[(size_t)v * 3 + lane];
}

// ---------------------------------------------------------------------------
extern "C" void kernel_launch(void* const* d_in, const int* in_sizes, int n_in,
                              void* d_out, int out_size, void* d_ws, size_t ws_size,
                              hipStream_t stream)
{
    const float* x    = (const float*)d_in[0];
    const int*   ei   = (const int*)d_in[1];
    const float* ea   = (const float*)d_in[2];
    const float* ci   = (const float*)d_in[3];
    const float* fc1w = (const float*)d_in[4];
    const float* fc1b = (const float*)d_in[5];
    const float* k1w  = (const float*)d_in[6];
    const float* k1b  = (const float*)d_in[7];
    const float* k2w  = (const float*)d_in[8];
    const float* k2b  = (const float*)d_in[9];
    const float* k3w  = (const float*)d_in[10];
    const float* k3b  = (const float*)d_in[11];
    const float* cm1w = (const float*)d_in[12];
    const float* cm1b = (const float*)d_in[13];
    const float* cm2w = (const float*)d_in[14];
    const float* cm2b = (const float*)d_in[15];
    const float* f2aw = (const float*)d_in[16];
    const float* f2ab = (const float*)d_in[17];
    const float* f2bw = (const float*)d_in[18];
    const float* f2bb = (const float*)d_in[19];

    // ---- workspace carve; tiers: A=(2,2) fp16/fp16, B=(1,2) u8/fp16, C=(1,1) u8/i8
    size_t o_k2, o_k2s, o_G, o_h, o_agg, o_bv, o_coord, o_dco, o_invc, o_rc,
           o_cc, o_cs, o_cn, o_el, o_ri, o_ci, o_gsc, o_giv, o_w3n;
#define ALGN(v) (((v) + 255) & ~(size_t)255)
    auto carve = [&](size_t k2es, size_t ges) -> size_t {
        size_t o = 0;
        o_k2   = o; o += ALGN((size_t)NE * 256 * k2es);
        o_k2s  = o; o += ALGN((size_t)NE * 4);
        o_G    = o; o += ALGN((size_t)NN * 8192 * ges);
        o_h    = o; o += ALGN((size_t)NN * 32 * 4);
        o_agg  = o; o += ALGN((size_t)NN * 32 * 4);
        o_bv   = o; o += ALGN((size_t)NN * 32 * 4);
        o_coord= o; o += ALGN((size_t)NN * 3 * 4);
        o_dco  = o; o += ALGN((size_t)NN * 3 * 4);
        o_invc = o; o += ALGN((size_t)NN * 4);
        o_rc   = o; o += ALGN((size_t)NN * 4);
        o_cc   = o; o += ALGN((size_t)NN * 4);
        o_cs   = o; o += ALGN((size_t)(NN + 1) * 4);
        o_cn   = o; o += ALGN((size_t)NN * 4);
        o_el   = o; o += ALGN((size_t)NE * 4);
        o_ri   = o; o += ALGN((size_t)NE * 4);
        o_ci   = o; o += ALGN((size_t)NE * 4);
        o_gsc  = o; o += ALGN((size_t)NN * 4);
        o_giv  = o; o += ALGN((size_t)NN * 4);
        o_w3n  = o; o += 256;
        return o;
    };
    int fk2, fG;
    if      (ws_size >= carve(2, 2)) { fk2 = 0; fG = 0; carve(2, 2); }  // ~328 MB
    else if (ws_size >= carve(1, 2)) { fk2 = 1; fG = 0; carve(1, 2); }  // ~251 MB
    else if (ws_size >= carve(1, 1)) { fk2 = 1; fG = 1; carve(1, 1); }  // ~169 MB
    else {
        sentinel_kernel<<<(NN * 4 + 255) / 256, 256, 0, stream>>>((float*)d_out, NN * 4, 1.0e6f);
        return;
    }

    char* wsb = (char*)d_ws;
    u8*    k2g   = (u8*)(wsb + o_k2);
    float* k2s   = (float*)(wsb + o_k2s);
    u8*    Gg    = (u8*)(wsb + o_G);
    float* h     = (float*)(wsb + o_h);
    float* agg   = (float*)(wsb + o_agg);
    float* bvec  = (float*)(wsb + o_bv);
    float* coord = (float*)(wsb + o_coord);
    float* dco   = (float*)(wsb + o_dco);
    float* invc  = (float*)(wsb + o_invc);
    int*   rowcnt= (int*)(wsb + o_rc);
    int*   colcnt= (int*)(wsb + o_cc);
    int*   cstart= (int*)(wsb + o_cs);
    int*   cnext = (int*)(wsb + o_cn);
    int*   elist = (int*)(wsb + o_el);
    int*   ridx  = (int*)(wsb + o_ri);
    int*   cidx  = (int*)(wsb + o_ci);
    float* gsc   = (float*)(wsb + o_gsc);
    float* ginv  = (float*)(wsb + o_giv);
    u32*   w3n   = (u32*)(wsb + o_w3n);

    hipMemsetAsync(agg,    0, (size_t)NN * 32 * 4, stream);
    hipMemsetAsync(dco,    0, (size_t)NN * 3 * 4, stream);
    hipMemsetAsync(rowcnt, 0, (size_t)NN * 4, stream);
    hipMemsetAsync(colcnt, 0, (size_t)NN * 4, stream);
    hipMemsetAsync(w3n,    0, 4, stream);

    detect_idx_kernel<<<1, 256, 0, stream>>>(ei, cnext);   // reuse cnext[0] as flag temp
    convert_idx_kernel<<<(2 * NE + 255) / 256, 256, 0, stream>>>(ei, cnext, ridx, cidx);
    init_nodes_kernel<<<(NN * 32 + 255) / 256, 256, 0, stream>>>(x, fc1w, fc1b, ci, h, coord);
    count_kernel<<<(NE + 255) / 256, 256, 0, stream>>>(ridx, cidx, rowcnt, colcnt);
    scan_kernel<<<1, 256, 0, stream>>>(colcnt, rowcnt, cstart, cnext, invc);
    scatter_kernel<<<(NE + 255) / 256, 256, 0, stream>>>(cidx, cnext, elist);
    mlp_k2_kernel<<<NE / 32, 256, 0, stream>>>(ea, k1w, k1b, k2w, k2b, k2g, k2s, fk2);
    w3norm_kernel<<<32, 256, 0, stream>>>(k3w, w3n);

    const dim3 ggrid((NN + 127) / 128, 16);
    for (int l = 0; l < DEPTH; l++) {
        bvec_kernel<<<(NN * 32 + 255) / 256, 256, 0, stream>>>(h, k3b, bvec);
        gscale_kernel<<<(NN + 255) / 256, 256, 0, stream>>>(h, w3n, gsc, ginv);
        g_kernel<<<ggrid, 256, 0, stream>>>(h, k3w, Gg, ginv, fG);
        edge_kernel<<<NN, 256, 0, stream>>>(cstart, elist, ridx, k2g, k2s, Gg, gsc,
                                            coord, cm1w, cm1b, cm2w, cm2b, bvec,
                                            agg, dco, fk2, fG);
        node_update_kernel<<<(NN * 32 + 255) / 256, 256, 0, stream>>>(h, agg, coord, dco, invc);
    }
    final_kernel<<<(NN + 3) / 4, 256, 0, stream>>>(h, coord, f2aw, f2ab, f2bw, f2bb,
                                                   (float*)d_out);
}

// Round 6
// 1463.513 us; speedup vs baseline: 1.7584x; 1.7584x over previous
//
#include <hip/hip_runtime.h>

// EGKN: E(n) graph kernel network.
#define NN 10000      // nodes
#define NE 300000     // edges
#define DEPTH 4

typedef unsigned int   u32;
typedef unsigned short u16;
typedef unsigned char  u8;

typedef _Float16 half8  __attribute__((ext_vector_type(8)));
typedef float  floatx16 __attribute__((ext_vector_type(16)));

// fp16 encode/decode via hardware v_cvt (with saturation on encode)
__device__ __forceinline__ u32 f2h(float f) {
    f = fminf(fmaxf(f, -60000.f), 60000.f);
    _Float16 h = (_Float16)f;
    return (u32)__builtin_bit_cast(u16, h);
}
__device__ __forceinline__ float h2f(u16 b) {
    return (float)__builtin_bit_cast(_Float16, b);
}

// ---------------------------------------------------------------------------
__global__ void sentinel_kernel(float* out, int n, float val) {
    int i = blockIdx.x * 256 + threadIdx.x;
    if (i < n) out[i] = val;
}

// ---------------------------------------------------------------------------
// edge_index dtype normalization (int64 vs int32)
// ---------------------------------------------------------------------------
__global__ void detect_idx_kernel(const int* __restrict__ ei, int* __restrict__ flag) {
    __shared__ int nz;
    if (threadIdx.x == 0) nz = 0;
    __syncthreads();
    if (ei[threadIdx.x * 2 + 1] != 0) atomicAdd(&nz, 1);
    __syncthreads();
    if (threadIdx.x == 0) *flag = (nz == 0) ? 1 : 0;   // 1 => int64
}

__global__ __launch_bounds__(256) void convert_idx_kernel(
    const int* __restrict__ ei, const int* __restrict__ flag,
    int* __restrict__ ridx, int* __restrict__ cidx)
{
    int e = blockIdx.x * 256 + threadIdx.x;
    if (e >= 2 * NE) return;
    const int is64 = *flag;
    int v = is64 ? ei[2 * e] : ei[e];
    if (e < NE) ridx[e] = v; else cidx[e - NE] = v;
}

// ---------------------------------------------------------------------------
// init: h = x @ fc1_w + fc1_b   [NN,32];  coord = coords_init copy
// ---------------------------------------------------------------------------
__global__ __launch_bounds__(256) void init_nodes_kernel(
    const float* __restrict__ x, const float* __restrict__ fc1w,
    const float* __restrict__ fc1b, const float* __restrict__ ci,
    float* __restrict__ h, float* __restrict__ coord)
{
    int idx = blockIdx.x * 256 + threadIdx.x;
    if (idx < NN * 32) {
        int v = idx >> 5, f = idx & 31;
        float acc = fc1b[f];
#pragma unroll
        for (int i = 0; i < 3; i++) acc += x[v * 3 + i] * fc1w[i * 32 + f];
        h[idx] = acc;
    }
    if (idx < NN * 3) coord[idx] = ci[idx];
}

// ---------------------------------------------------------------------------
// CSR-by-col build: counts, scan, scatter
// ---------------------------------------------------------------------------
__global__ __launch_bounds__(256) void count_kernel(
    const int* __restrict__ ridx, const int* __restrict__ cidx,
    int* __restrict__ rowcnt, int* __restrict__ colcnt)
{
    int e = blockIdx.x * 256 + threadIdx.x;
    if (e < NE) { atomicAdd(&rowcnt[ridx[e]], 1); atomicAdd(&colcnt[cidx[e]], 1); }
}

__global__ void scan_kernel(const int* __restrict__ colcnt, const int* __restrict__ rowcnt,
                            int* __restrict__ cstart, int* __restrict__ cnext,
                            float* __restrict__ invc)
{
    __shared__ int part[256];
    const int t = threadIdx.x;
    int sum = 0;
    for (int i = 0; i < 40; i++) { int v = t * 40 + i; if (v < NN) sum += colcnt[v]; }
    part[t] = sum;
    __syncthreads();
    if (t == 0) {
        int run = 0;
        for (int i = 0; i < 256; i++) { int tmp = part[i]; part[i] = run; run += tmp; }
    }
    __syncthreads();
    int run = part[t];
    for (int i = 0; i < 40; i++) {
        int v = t * 40 + i;
        if (v < NN) { cstart[v] = run; cnext[v] = run; run += colcnt[v]; }
    }
    if (t == 255) cstart[NN] = run;
    for (int v = t; v < NN; v += 256) invc[v] = 1.0f / fmaxf((float)rowcnt[v], 1.0f);
}

__global__ __launch_bounds__(256) void scatter_kernel(
    const int* __restrict__ cidx, int* __restrict__ cnext, int* __restrict__ elist)
{
    int e = blockIdx.x * 256 + threadIdx.x;
    if (e < NE) { int pos = atomicAdd(&cnext[cidx[e]], 1); elist[pos] = e; }
}

// ---------------------------------------------------------------------------
// k2 MLP: edge_attr[6] -> 128 -> 256 (relu both). 32 edges/block.
// fk2=0: fp16 [e][256].  fk2=1: uint8 [e][256] + per-edge scale k2s[e].
// ---------------------------------------------------------------------------
__global__ __launch_bounds__(256) void mlp_k2_kernel(
    const float* __restrict__ ea,
    const float* __restrict__ w1, const float* __restrict__ b1,
    const float* __restrict__ w2, const float* __restrict__ b2,
    u8* __restrict__ k2base, float* __restrict__ k2s, int fk2)
{
    __shared__ __align__(16) float ea_s[32 * 6];
    __shared__ __align__(16) float k1_s[128 * 32];     // [kk][e]
    __shared__ __align__(16) float k2_s[32 * 260];     // [e][c], padded
    const int t  = threadIdx.x;
    const int e0 = blockIdx.x * 32;

    for (int idx = t; idx < 32 * 6; idx += 256)
        ea_s[idx] = ea[(size_t)e0 * 6 + idx];
    __syncthreads();

    // layer 1: [32,6] @ [6,128], relu
    for (int idx = t; idx < 128 * 32; idx += 256) {
        int kk = idx >> 5, e = idx & 31;
        float acc = b1[kk];
#pragma unroll
        for (int i = 0; i < 6; i++) acc += ea_s[e * 6 + i] * w1[i * 128 + kk];
        k1_s[kk * 32 + e] = fmaxf(acc, 0.f);
    }
    __syncthreads();

    // layer 2: [32,128] @ [128,256], relu. thread tile: 4 cols x 8 edges
    {
        const int c0 = (t & 63) * 4;
        const int eb = (t >> 6) * 8;
        float acc[4][8];
#pragma unroll
        for (int a = 0; a < 4; a++)
#pragma unroll
            for (int b = 0; b < 8; b++) acc[a][b] = 0.f;
        for (int kk = 0; kk < 128; kk++) {
            const float4 wv = *(const float4*)&w2[kk * 256 + c0];
            const float4 ka = *(const float4*)&k1_s[kk * 32 + eb];
            const float4 kb = *(const float4*)&k1_s[kk * 32 + eb + 4];
            const float ke[8] = {ka.x, ka.y, ka.z, ka.w, kb.x, kb.y, kb.z, kb.w};
            const float wc[4] = {wv.x, wv.y, wv.z, wv.w};
#pragma unroll
            for (int a = 0; a < 4; a++)
#pragma unroll
                for (int b = 0; b < 8; b++) acc[a][b] += wc[a] * ke[b];
        }
        const float bb0 = b2[c0], bb1 = b2[c0 + 1], bb2 = b2[c0 + 2], bb3 = b2[c0 + 3];
#pragma unroll
        for (int b = 0; b < 8; b++) {
            float4 v;
            v.x = fmaxf(acc[0][b] + bb0, 0.f);
            v.y = fmaxf(acc[1][b] + bb1, 0.f);
            v.z = fmaxf(acc[2][b] + bb2, 0.f);
            v.w = fmaxf(acc[3][b] + bb3, 0.f);
            *(float4*)&k2_s[(eb + b) * 260 + c0] = v;
        }
    }
    __syncthreads();

    // store k2: thread t -> edge el=t>>3, col-chunk q=t&7 (32 cols each)
    {
        const int el = t >> 3, q = t & 7;
        const size_t eglob = (size_t)e0 + el;
        if (fk2 == 0) {
            u16* outp = (u16*)k2base + eglob * 256 + q * 32;
#pragma unroll
            for (int u = 0; u < 8; u += 2) {
                float4 a = *(float4*)&k2_s[el * 260 + q * 32 + u * 4];
                float4 b = *(float4*)&k2_s[el * 260 + q * 32 + u * 4 + 4];
                uint4 o;
                o.x = f2h(a.x) | (f2h(a.y) << 16);
                o.y = f2h(a.z) | (f2h(a.w) << 16);
                o.z = f2h(b.x) | (f2h(b.y) << 16);
                o.w = f2h(b.z) | (f2h(b.w) << 16);
                *(uint4*)(outp + u * 4) = o;
            }
        } else {
            // per-edge max over the 8 lanes covering this edge
            float mx = 0.f;
#pragma unroll
            for (int u = 0; u < 32; u++) mx = fmaxf(mx, k2_s[el * 260 + q * 32 + u]);
            mx = fmaxf(mx, __shfl_xor(mx, 1, 8));
            mx = fmaxf(mx, __shfl_xor(mx, 2, 8));
            mx = fmaxf(mx, __shfl_xor(mx, 4, 8));
            const float sc  = mx / 255.f;
            const float inv = (mx > 0.f) ? 255.f / mx : 0.f;
            if (q == 0) k2s[eglob] = sc;
            u8* outp = k2base + eglob * 256 + q * 32;
            u32 w[8];
#pragma unroll
            for (int u = 0; u < 8; u++) {
                float4 a = *(float4*)&k2_s[el * 260 + q * 32 + u * 4];
                u32 q0 = (u32)fminf(rintf(a.x * inv), 255.f);
                u32 q1 = (u32)fminf(rintf(a.y * inv), 255.f);
                u32 q2 = (u32)fminf(rintf(a.z * inv), 255.f);
                u32 q3 = (u32)fminf(rintf(a.w * inv), 255.f);
                w[u] = q0 | (q1 << 8) | (q2 << 16) | (q3 << 24);
            }
            *(uint4*)outp        = make_uint4(w[0], w[1], w[2], w[3]);
            *(uint4*)(outp + 16) = make_uint4(w[4], w[5], w[6], w[7]);
        }
    }
}

// ---------------------------------------------------------------------------
// Bvec[v][i] = sum_j b3[i*32+j] * h[v][j]
// ---------------------------------------------------------------------------
__global__ __launch_bounds__(256) void bvec_kernel(
    const float* __restrict__ h, const float* __restrict__ b3, float* __restrict__ bvec)
{
    int idx = blockIdx.x * 256 + threadIdx.x;
    if (idx >= NN * 32) return;
    int v = idx >> 5, i = idx & 31;
    const float* hp = &h[(size_t)v * 32];
    const float* bp = &b3[i * 32];
    float acc = 0.f;
#pragma unroll
    for (int c = 0; c < 8; c++) {
        float4 hv = *(const float4*)&hp[c * 4];
        float4 bv = *(const float4*)&bp[c * 4];
        acc += hv.x * bv.x + hv.y * bv.y + hv.z * bv.z + hv.w * bv.w;
    }
    bvec[idx] = acc;
}

// ---------------------------------------------------------------------------
// G in MFMA-B-fragment order, fp16.
// u16 offset within node row (8192): o = s*512 + lane*8 + j, where the MFMA
// B operand for step s has lane `lane` holding G[k = s*16+(lane>>5)*8+j][i=lane&31],
// with G[v][k*32+i] = sum_j w3[k*1024 + i*32 + jj] * h[v][jj].
// Thread t of y-block `by` (= step s) computes j0=2*(t&3), j0+1 for lane t>>2,
// i.e. weight rows k0, k0+1 -> one u32 store at u32-index v*4096 + by*256 + t.
// ---------------------------------------------------------------------------
__global__ __launch_bounds__(256) void g_kernel(
    const float* __restrict__ h, const float* __restrict__ w3,
    u16* __restrict__ Gg)
{
    __shared__ __align__(16) float h_s[128 * 32];
    const int t  = threadIdx.x;
    const int v0 = blockIdx.x * 128;

    for (int i = t; i < 128 * 8; i += 256) {
        const int v = i >> 3, c = i & 7;
        float4 val = make_float4(0.f, 0.f, 0.f, 0.f);
        if (v0 + v < NN) val = *(const float4*)&h[(size_t)(v0 + v) * 32 + c * 4];
        *(float4*)&h_s[v * 32 + c * 4] = val;
    }
    __syncthreads();

    const int by    = blockIdx.y;        // step s, 0..15
    const int lane  = t >> 2;            // 0..63
    const int i     = lane & 31;
    const int halfk = lane >> 5;
    const int j0    = (t & 3) * 2;
    const int k0    = by * 16 + halfk * 8 + j0;

    float w0[32], w1[32];
    {
        const float* wp0 = &w3[(size_t)k0 * 1024 + (size_t)i * 32];
        const float* wp1 = wp0 + 1024;
#pragma unroll
        for (int c = 0; c < 8; c++) {
            float4 a = *(const float4*)&wp0[c * 4];
            w0[c * 4] = a.x; w0[c * 4 + 1] = a.y; w0[c * 4 + 2] = a.z; w0[c * 4 + 3] = a.w;
            float4 b = *(const float4*)&wp1[c * 4];
            w1[c * 4] = b.x; w1[c * 4 + 1] = b.y; w1[c * 4 + 2] = b.z; w1[c * 4 + 3] = b.w;
        }
    }
    const int vmax = min(128, NN - v0);
    u32* outp = (u32*)Gg;
    for (int v = 0; v < vmax; v++) {
        float a0 = 0.f, a1 = 0.f;
#pragma unroll
        for (int c = 0; c < 8; c++) {
            float4 hv = *(const float4*)&h_s[v * 32 + c * 4];
            a0 += hv.x * w0[c*4] + hv.y * w0[c*4+1] + hv.z * w0[c*4+2] + hv.w * w0[c*4+3];
            a1 += hv.x * w1[c*4] + hv.y * w1[c*4+1] + hv.z * w1[c*4+2] + hv.w * w1[c*4+3];
        }
        outp[(size_t)(v0 + v) * 4096 + by * 256 + t] = f2h(a0) | (f2h(a1) << 16);
    }
}

// ---------------------------------------------------------------------------
// MFMA edge pass. One wave64 per col-node n; 4 waves/block (independent).
// Per 32-edge tile:
//   M[32e][32i] = bv[i] + K2[32e,256] @ G_n[256,32]    (16x mfma_32x32x16_f16)
//   T[32e][32q] = cm1b[q] + M @ cm1                    (LDS roundtrip + 2 mfma)
//   we[e] = relu-row-dot(T, cm2) + cm2b                 (shfl_xor reduce)
//   atomics: agg[row_e] += M row; dco[row_e] += (coord[row_e]-coord[n])*we
// C/D layout: col = lane&31, row = (reg&3)+8*(reg>>2)+4*(lane>>5).
// ---------------------------------------------------------------------------
__global__ __launch_bounds__(256) void edge_kernel(
    const int* __restrict__ cstart, const int* __restrict__ elist,
    const int* __restrict__ ridx, const u8* __restrict__ k2base,
    const float* __restrict__ k2s, const u16* __restrict__ Gg,
    const float* __restrict__ coord,
    const float* __restrict__ cm1w, const float* __restrict__ cm1b,
    const float* __restrict__ cm2w, const float* __restrict__ cm2b,
    const float* __restrict__ bvec, float* __restrict__ agg,
    float* __restrict__ dco, int fk2)
{
    const int t    = threadIdx.x;
    const int w    = t >> 6;         // wave in block
    const int l    = t & 63;         // lane
    const int li   = l & 31;         // column index / lane-in-half
    const int half = l >> 5;

    __shared__ __align__(16) float Mlds_all[4][32 * 36];
    float* Mlds = Mlds_all[w];

    // cm1 B-fragments + cm2 (node-independent)
    half8 cmb[2];
#pragma unroll
    for (int s2 = 0; s2 < 2; s2++)
#pragma unroll
        for (int j = 0; j < 8; j++)
            cmb[s2][j] = (_Float16)cm1w[(s2 * 16 + half * 8 + j) * 32 + li];
    const float cm1bq = cm1b[li];
    const float cm2q  = cm2w[li];
    const float cm2b0 = cm2b[0];

    const int n = blockIdx.x * 4 + w;
    if (n >= NN) return;
    const int s0  = cstart[n];
    const int deg = cstart[n + 1] - s0;
    if (deg == 0) return;

    const float bv  = bvec[n * 32 + li];
    const float con = (li < 3) ? coord[(size_t)n * 3 + li] : 0.f;
    const u16* Gn = Gg + (size_t)n * 8192;

    for (int base = 0; base < deg; base += 32) {
        const int mye   = base + li;
        const int valid = (mye < deg) ? 1 : 0;
        const int eid   = valid ? elist[s0 + mye] : 0;
        const int rowv  = valid ? ridx[eid] : 0;

        floatx16 acc;
#pragma unroll
        for (int r = 0; r < 16; r++) acc[r] = bv;

        if (fk2 == 1) {
            const float se = valid ? k2s[eid] : 0.f;
            const u8* k2row = k2base + (size_t)eid * 256 + half * 8;
#pragma unroll
            for (int s = 0; s < 16; s++) {
                const uint2 wd = *(const uint2*)(k2row + s * 16);
                half8 a;
#pragma unroll
                for (int j = 0; j < 4; j++) {
                    a[j]     = (_Float16)((float)((wd.x >> (8 * j)) & 0xffu) * se);
                    a[4 + j] = (_Float16)((float)((wd.y >> (8 * j)) & 0xffu) * se);
                }
                const half8 b = __builtin_bit_cast(half8,
                    *(const uint4*)(Gn + s * 512 + l * 8));
                acc = __builtin_amdgcn_mfma_f32_32x32x16_f16(a, b, acc, 0, 0, 0);
            }
        } else {
            const u16* k2row = (const u16*)k2base + (size_t)eid * 256 + half * 8;
#pragma unroll
            for (int s = 0; s < 16; s++) {
                const half8 a = __builtin_bit_cast(half8, *(const uint4*)(k2row + s * 16));
                const half8 b = __builtin_bit_cast(half8,
                    *(const uint4*)(Gn + s * 512 + l * 8));
                acc = __builtin_amdgcn_mfma_f32_32x32x16_f16(a, b, acc, 0, 0, 0);
            }
            // invalid lanes computed garbage M rows from edge 0's k2 — they are
            // skipped in the epilogue (valid flag), values stay finite.
        }

        // M -> LDS (fp32, stride 36 for bank spread / 16B alignment)
#pragma unroll
        for (int r = 0; r < 16; r++) {
            const int e = (r & 3) + 8 * (r >> 2) + 4 * half;
            Mlds[e * 36 + li] = acc[r];
        }
        asm volatile("s_waitcnt lgkmcnt(0)" ::: "memory");

        // T = cm1b + M @ cm1
        floatx16 acc2;
#pragma unroll
        for (int r = 0; r < 16; r++) acc2[r] = cm1bq;
#pragma unroll
        for (int s2 = 0; s2 < 2; s2++) {
            const float* mp = &Mlds[li * 36 + s2 * 16 + half * 8];
            const float4 m0 = *(const float4*)mp;
            const float4 m1 = *(const float4*)(mp + 4);
            half8 a;
            a[0] = (_Float16)m0.x; a[1] = (_Float16)m0.y;
            a[2] = (_Float16)m0.z; a[3] = (_Float16)m0.w;
            a[4] = (_Float16)m1.x; a[5] = (_Float16)m1.y;
            a[6] = (_Float16)m1.z; a[7] = (_Float16)m1.w;
            acc2 = __builtin_amdgcn_mfma_f32_32x32x16_f16(a, cmb[s2], acc2, 0, 0, 0);
        }

        // epilogue: per C-reg r -> edge e; we-reduction + atomics
#pragma unroll
        for (int r = 0; r < 16; r++) {
            const int e  = (r & 3) + 8 * (r >> 2) + 4 * half;
            const int vr = __shfl(valid, e, 32);
            const int rr = __shfl(rowv, e, 32);
            float part = fmaxf(acc2[r], 0.f) * cm2q;
            part += __shfl_xor(part, 1, 32);
            part += __shfl_xor(part, 2, 32);
            part += __shfl_xor(part, 4, 32);
            part += __shfl_xor(part, 8, 32);
            part += __shfl_xor(part, 16, 32);
            const float wer = part + cm2b0;
            if (vr) {
                atomicAdd(&agg[(size_t)rr * 32 + li], acc[r]);
                if (li < 3) {
                    const float d = coord[(size_t)rr * 3 + li] - con;
                    atomicAdd(&dco[(size_t)rr * 3 + li], d * wer);
                }
            }
        }
    }
}

// ---------------------------------------------------------------------------
__global__ __launch_bounds__(256) void node_update_kernel(
    float* __restrict__ h, float* __restrict__ agg,
    float* __restrict__ coord, float* __restrict__ dco,
    const float* __restrict__ invc)
{
    int idx = blockIdx.x * 256 + threadIdx.x;
    if (idx < NN * 32) {
        int v = idx >> 5;
        h[idx] = fmaxf(h[idx] + agg[idx] * invc[v], 0.f);
        agg[idx] = 0.f;
    }
    if (idx < NN * 3) {
        coord[idx] += dco[idx] * invc[idx / 3];
        dco[idx] = 0.f;
    }
}

// ---------------------------------------------------------------------------
__global__ __launch_bounds__(256) void final_kernel(
    const float* __restrict__ h, const float* __restrict__ coord,
    const float* __restrict__ wa, const float* __restrict__ ba,
    const float* __restrict__ wb, const float* __restrict__ bb,
    float* __restrict__ out)
{
    const int lane = threadIdx.x & 63;
    const int v = blockIdx.x * 4 + (threadIdx.x >> 6);
    if (v >= NN) return;
    const float hreg = (lane < 32) ? h[(size_t)v * 32 + lane] : 0.f;
    float acc = ba[lane];
#pragma unroll
    for (int f = 0; f < 32; f++) acc += __shfl(hreg, f, 64) * wa[f * 64 + lane];
    float part = fmaxf(acc, 0.f) * wb[lane];
#pragma unroll
    for (int off = 32; off >= 1; off >>= 1) part += __shfl_xor(part, off, 64);
    if (lane == 0) out[v] = part + bb[0];
    if (lane < 3) out[NN + (size_t)v * 3 + lane] = coord[(size_t)v * 3 + lane];
}

// ---------------------------------------------------------------------------
extern "C" void kernel_launch(void* const* d_in, const int* in_sizes, int n_in,
                              void* d_out, int out_size, void* d_ws, size_t ws_size,
                              hipStream_t stream)
{
    const float* x    = (const float*)d_in[0];
    const int*   ei   = (const int*)d_in[1];
    const float* ea   = (const float*)d_in[2];
    const float* ci   = (const float*)d_in[3];
    const float* fc1w = (const float*)d_in[4];
    const float* fc1b = (const float*)d_in[5];
    const float* k1w  = (const float*)d_in[6];
    const float* k1b  = (const float*)d_in[7];
    const float* k2w  = (const float*)d_in[8];
    const float* k2b  = (const float*)d_in[9];
    const float* k3w  = (const float*)d_in[10];
    const float* k3b  = (const float*)d_in[11];
    const float* cm1w = (const float*)d_in[12];
    const float* cm1b = (const float*)d_in[13];
    const float* cm2w = (const float*)d_in[14];
    const float* cm2b = (const float*)d_in[15];
    const float* f2aw = (const float*)d_in[16];
    const float* f2ab = (const float*)d_in[17];
    const float* f2bw = (const float*)d_in[18];
    const float* f2bb = (const float*)d_in[19];

    // ---- workspace carve; tiers: A=(2) fp16 k2, B=(1) u8 k2. G always fp16.
    size_t o_k2, o_k2s, o_G, o_h, o_agg, o_bv, o_coord, o_dco, o_invc, o_rc,
           o_cc, o_cs, o_cn, o_el, o_ri, o_ci;
#define ALGN(v) (((v) + 255) & ~(size_t)255)
    auto carve = [&](size_t k2es) -> size_t {
        size_t o = 0;
        o_k2   = o; o += ALGN((size_t)NE * 256 * k2es);
        o_k2s  = o; o += ALGN((size_t)NE * 4);
        o_G    = o; o += ALGN((size_t)NN * 8192 * 2);
        o_h    = o; o += ALGN((size_t)NN * 32 * 4);
        o_agg  = o; o += ALGN((size_t)NN * 32 * 4);
        o_bv   = o; o += ALGN((size_t)NN * 32 * 4);
        o_coord= o; o += ALGN((size_t)NN * 3 * 4);
        o_dco  = o; o += ALGN((size_t)NN * 3 * 4);
        o_invc = o; o += ALGN((size_t)NN * 4);
        o_rc   = o; o += ALGN((size_t)NN * 4);
        o_cc   = o; o += ALGN((size_t)NN * 4);
        o_cs   = o; o += ALGN((size_t)(NN + 1) * 4);
        o_cn   = o; o += ALGN((size_t)NN * 4);
        o_el   = o; o += ALGN((size_t)NE * 4);
        o_ri   = o; o += ALGN((size_t)NE * 4);
        o_ci   = o; o += ALGN((size_t)NE * 4);
        return o;
    };
    int fk2;
    if      (ws_size >= carve(2)) { fk2 = 0; carve(2); }  // ~328 MB
    else if (ws_size >= carve(1)) { fk2 = 1; carve(1); }  // ~251 MB
    else {
        sentinel_kernel<<<(NN * 4 + 255) / 256, 256, 0, stream>>>((float*)d_out, NN * 4, 1.0e6f);
        return;
    }

    char* wsb = (char*)d_ws;
    u8*    k2g   = (u8*)(wsb + o_k2);
    float* k2s   = (float*)(wsb + o_k2s);
    u16*   Gg    = (u16*)(wsb + o_G);
    float* h     = (float*)(wsb + o_h);
    float* agg   = (float*)(wsb + o_agg);
    float* bvec  = (float*)(wsb + o_bv);
    float* coord = (float*)(wsb + o_coord);
    float* dco   = (float*)(wsb + o_dco);
    float* invc  = (float*)(wsb + o_invc);
    int*   rowcnt= (int*)(wsb + o_rc);
    int*   colcnt= (int*)(wsb + o_cc);
    int*   cstart= (int*)(wsb + o_cs);
    int*   cnext = (int*)(wsb + o_cn);
    int*   elist = (int*)(wsb + o_el);
    int*   ridx  = (int*)(wsb + o_ri);
    int*   cidx  = (int*)(wsb + o_ci);

    hipMemsetAsync(agg,    0, (size_t)NN * 32 * 4, stream);
    hipMemsetAsync(dco,    0, (size_t)NN * 3 * 4, stream);
    hipMemsetAsync(rowcnt, 0, (size_t)NN * 4, stream);
    hipMemsetAsync(colcnt, 0, (size_t)NN * 4, stream);

    detect_idx_kernel<<<1, 256, 0, stream>>>(ei, cnext);   // cnext[0] as flag temp
    convert_idx_kernel<<<(2 * NE + 255) / 256, 256, 0, stream>>>(ei, cnext, ridx, cidx);
    init_nodes_kernel<<<(NN * 32 + 255) / 256, 256, 0, stream>>>(x, fc1w, fc1b, ci, h, coord);
    count_kernel<<<(NE + 255) / 256, 256, 0, stream>>>(ridx, cidx, rowcnt, colcnt);
    scan_kernel<<<1, 256, 0, stream>>>(colcnt, rowcnt, cstart, cnext, invc);
    scatter_kernel<<<(NE + 255) / 256, 256, 0, stream>>>(cidx, cnext, elist);
    mlp_k2_kernel<<<NE / 32, 256, 0, stream>>>(ea, k1w, k1b, k2w, k2b, k2g, k2s, fk2);

    const dim3 ggrid((NN + 127) / 128, 16);
    for (int l = 0; l < DEPTH; l++) {
        bvec_kernel<<<(NN * 32 + 255) / 256, 256, 0, stream>>>(h, k3b, bvec);
        g_kernel<<<ggrid, 256, 0, stream>>>(h, k3w, Gg);
        edge_kernel<<<(NN + 3) / 4, 256, 0, stream>>>(cstart, elist, ridx, k2g, k2s,
                                                      Gg, coord, cm1w, cm1b, cm2w, cm2b,
                                                      bvec, agg, dco, fk2);
        node_update_kernel<<<(NN * 32 + 255) / 256, 256, 0, stream>>>(h, agg, coord, dco, invc);
    }
    final_kernel<<<(NN + 3) / 4, 256, 0, stream>>>(h, coord, f2aw, f2ab, f2bw, f2bb,
                                                   (float*)d_out);
}